// Round 6
// baseline (808.997 us; speedup 1.0000x reference)
//
#include <hip/hip_runtime.h>
#include <cmath>

#define NS 64
#define NN 128
#define NT 1000
#define CH 8                                // steps per obuf half-buffer
#define ROWDW (NN * 3 + 8)                  // 392 dwords per buffered step-row
#define WROWS 130                           // 128 rows of w + 2 zero rows
#define WL_DW (WROWS * NN)                  // 16640
#define OBUF_DW (2 * CH * ROWDW)            // 6272 (double-buffered)
#define NRING_DW (16 * 256)                 // 16 slots x 1KB noise rows
#define ERING_DW (16 * 128)                 // 16 slots x 512B exp rows
#define LDS_BYTES ((WL_DW + OBUF_DW + NRING_DW + ERING_DW) * 4)   // 116224

// == npy_logaddexpf(x, 0), branch-free but bit-identical:
//   x>0: fmax=x, |x|=x  -> x + log1p(exp(-x)) ; x<0: 0 + log1p(exp(x)) ; x==0 -> LOGE2
__device__ __forceinline__ float softplus_np(float x) {
    float r = fmaxf(x, 0.0f) + log1pf(expf(-fabsf(x)));
    return (x == 0.0f) ? 0.693147180559945309f : r;
}

// Barrier WITHOUT the compiler's vmcnt(0) drain: LDS-visibility only.
__device__ __forceinline__ void sync_lds() {
    __builtin_amdgcn_sched_barrier(0);
    asm volatile("s_waitcnt lgkmcnt(0)" ::: "memory");
    __builtin_amdgcn_s_barrier();
    __builtin_amdgcn_sched_barrier(0);
}

// async global->LDS, 16B/lane; LDS dest = wave-uniform base + lane*16 (m104)
__device__ __forceinline__ void g2l16(const float* g, float* l) {
    __builtin_amdgcn_global_load_lds(
        (const __attribute__((address_space(1))) void*)g,
        (__attribute__((address_space(3))) void*)l,
        16, 0, 0);
}

__global__ __launch_bounds__(128) void snn_scan_kernel(
    const float* __restrict__ w,
    const float* __restrict__ ic,
    const float* __restrict__ v0,
    const float* __restrict__ i0,
    const float* __restrict__ s0,
    const float* __restrict__ mu,
    const float* __restrict__ sigma,
    const float* __restrict__ noise,      // [T, S, N, 2]
    const float* __restrict__ exp_draws,  // [T, S, N]
    float* __restrict__ out)              // [S, N, T, 3]
{
    #pragma clang fp contract(off)
    extern __shared__ float smem[];
    float* wl    = smem;                  // [130][128]: w rows + 2 zero rows
    float* obuf  = smem + WL_DW;          // [2][CH][ROWDW] output staging
    float* nring = smem + WL_DW + OBUF_DW;             // [16][256] noise rows
    float* ering = smem + WL_DW + OBUF_DW + NRING_DW;  // [16][128] exp rows

    const int samp = blockIdx.x;
    const int tid  = threadIdx.x;
    const int wid  = tid >> 6;            // wave 0 = compute, wave 1 = flush
    const int l    = tid & 63;

    {   // cooperative stage of w (4096 float4 / 128 threads) + zero rows
        const float4* src = (const float4*)w;
        float4* dst = (float4*)wl;
        #pragma unroll
        for (int it = 0; it < 32; ++it)
            dst[it * 128 + tid] = src[it * 128 + tid];
        ((float2*)(wl + 128 * NN))[tid] = make_float2(0.0f, 0.0f);
    }

    const float SQDT  = sqrtf(0.01f);     // 0x3DCCCCCD == np.sqrt(float32(0.01))
    const float DTf   = 0.01f;
    const float LOGE2 = 0.693147180559945309f;

    const float* nrow0 = noise + (size_t)samp * (NN * 2) + 4 * l;      // +t*S*N*2
    const float* erow0 = exp_draws + (size_t)samp * NN + 4 * l;        // +t*S*N
    float* outb = out + (size_t)samp * NN * NT * 3;

    float mu1 = 0.f, negmu2 = 0.f, g00 = 0.f, g01 = 0.f, g10 = 0.f, g11 = 0.f;
    float ic0 = 0.f, ic1 = 0.f;
    float v_0 = 0.f, v_1 = 0.f, i_0 = 0.f, i_1 = 0.f, s_0 = 0.f, s_1 = 0.f;
    float sp_0 = 0.f, sp_1 = 0.f;

    if (wid == 0) {
        __builtin_amdgcn_s_setprio(1);    // compute wave owns the critical path
        mu1 = mu[0]; negmu2 = -mu[1];
        g00 = sigma[0]; g01 = sigma[1]; g10 = sigma[2]; g11 = sigma[3];
        ic0 = ic[2 * l]; ic1 = ic[2 * l + 1];
        v_0 = v0[samp * NN + 2 * l]; v_1 = v0[samp * NN + 2 * l + 1];
        i_0 = i0[samp * NN + 2 * l]; i_1 = i0[samp * NN + 2 * l + 1];
        s_0 = s0[samp * NN + 2 * l]; s_1 = s0[samp * NN + 2 * l + 1];
        sp_0 = softplus_np(v_0); sp_1 = softplus_np(v_1);

        // prologue: 8 slot-pairs in flight (16 vm ops), FIFO order n,e,n,e,...
        #pragma unroll
        for (int t = 0; t < 8; ++t) {
            g2l16(nrow0 + (size_t)t * (NS * NN * 2), nring + t * 256);
            if (l < 32)
                g2l16(erow0 + (size_t)t * (NS * NN), ering + t * 128);
        }
    }
    sync_lds();   // w visible; ring loads stay in flight (lgkm-only barrier)

    const float2* wl2 = (const float2*)wl;

    auto doStep = [&](int tm, int csb, int psb, int tpf, float* orow) {
        #pragma clang fp contract(off)
        // retire exactly this step's slot pair (conservative-safe count)
        asm volatile("s_waitcnt vmcnt(14)" ::: "memory");
        __builtin_amdgcn_sched_barrier(0);
        const float4 nz = *(const float4*)(nring + (csb + tm) * 256 + 4 * l);
        const float2 ed = *(const float2*)(ering + (csb + tm) * 128 + 2 * l);

        // issue t+8 pair immediately (clamped at tail to keep FIFO invariant)
        const int tc = tpf < NT ? tpf : NT - 1;
        g2l16(nrow0 + (size_t)tc * (NS * NN * 2), nring + (psb + tm) * 256);
        if (l < 32)
            g2l16(erow0 + (size_t)tc * (NS * NN), ering + (psb + tm) * 128);

        const float dw00 = nz.x * SQDT, dw01 = nz.y * SQDT;
        const float dw10 = nz.z * SQDT, dw11 = nz.w * SQDT;

        const float nv0 = (dw00 * g00) + (dw01 * g01);
        const float nv1 = (dw10 * g00) + (dw11 * g01);
        const float ni0 = (dw00 * g10) + (dw01 * g11);
        const float ni1 = (dw10 * g10) + (dw11 * g11);

        const float t0 = (i_0 + ic0) - v_0;
        const float t1 = (i_1 + ic1) - v_1;
        const float vt0 = (v_0 + DTf * (mu1 * t0)) + nv0;
        const float vt1 = (v_1 + DTf * (mu1 * t1)) + nv1;
        const float it0 = (i_0 + DTf * (negmu2 * i_0)) + ni0;
        const float it1 = (i_1 + DTf * (negmu2 * i_1)) + ni1;
        s_0 = s_0 + DTf * sp_0;           // sp_* = softplus(carry v), pipelined
        s_1 = s_1 + DTf * sp_1;

        const bool k0 = (s_0 >= 0.0f), k1 = (s_1 >= 0.0f);
        unsigned long long me = __ballot(k0);   // bit b -> neuron 2b
        unsigned long long mo = __ballot(k1);   // bit b -> neuron 2b+1

        // speculative next-step softplus; VALU issue overlaps coupling LDS wait
        const float spv0 = softplus_np(vt0);
        const float spv1 = softplus_np(vt1);

        float a0 = 0.0f, a1 = 0.0f;
        if (me | mo) {                    // wave-uniform skip of empty steps
            auto ext1 = [&]() -> int {    // ascending-order extraction;
                const int be = me ? (int)__builtin_ctzll(me) : 64;   // empty ->
                const int bo = mo ? (int)__builtin_ctzll(mo) : 64;   // zero-rows
                const int ce = 2 * be, co = 2 * bo + 1;
                const bool te = ce < co;
                const unsigned long long me2 = me & (me - 1);
                const unsigned long long mo2 = mo & (mo - 1);
                me = te ? me2 : me;
                mo = te ? mo : mo2;
                return te ? ce : co;
            };
            const int r1 = ext1(); const int r2 = ext1();
            const int r3 = ext1(); const int r4 = ext1();
            const float2 q1 = wl2[r1 * 64 + l];   // 4 independent ds_read_b64
            const float2 q2 = wl2[r2 * 64 + l];
            const float2 q3 = wl2[r3 * 64 + l];
            const float2 q4 = wl2[r4 * 64 + l];
            a0 = q1.x;  a1 = q1.y;                // ascending-order fp32 sum
            a0 += q2.x; a1 += q2.y;
            a0 += q3.x; a1 += q3.y;
            a0 += q4.x; a1 += q4.y;
            if (me | mo) {                        // >=5 spikes: rare
                do {
                    const int r = ext1();
                    const float2 q = wl2[r * 64 + l];
                    a0 += q.x; a1 += q.y;
                } while (me | mo);
            }
        }
        i_0 = it0 + a0;                   // unconditional add: bit-identical
        i_1 = it1 + a1;

        v_0 = k0 ? 0.0f : vt0;      v_1 = k1 ? 0.0f : vt1;
        s_0 = k0 ? -ed.x : s_0;     s_1 = k1 ? -ed.y : s_1;
        sp_0 = k0 ? LOGE2 : spv0;   sp_1 = k1 ? LOGE2 : spv1;

        float* row = orow + tm * ROWDW;
        *(float2*)(row)     = make_float2(v_0, i_0);
        *(float2*)(row + 2) = make_float2(s_0, v_1);
        *(float2*)(row + 4) = make_float2(i_1, s_1);
    };

    auto flushBuf = [&](int b, int tb0) {
        // CH steps x 128 neurons x 12B; each neuron's run ([CH][3] dwords = 96B)
        // contiguous in global at outb + n*NT*3 + tb0*3
        const float* ob = obuf + b * (CH * ROWDW);
        #pragma unroll
        for (int j = 0; j < 24; ++j) {
            const int f = j * 64 + l;        // float2 slot 0..1535
            const int n = f / 12;            // neuron
            const int r = f - n * 12;        // float2 slot within run
            const int da = 2 * r;
            const float x = ob[((da    ) / 3) * ROWDW + n * 3 + ((da    ) % 3)];
            const float y = ob[((da + 1) / 3) * ROWDW + n * 3 + ((da + 1) % 3)];
            *(float2*)(outb + (size_t)n * (NT * 3) + (size_t)tb0 * 3 + da) =
                make_float2(x, y);
        }
    };

    int cur = 0;
    for (int tb = 0; tb < NT; tb += CH) {
        if (wid == 0) {
            float* orow = obuf + cur * (CH * ROWDW) + 6 * l;
            const int sb = tb & 8;        // consume ring half
            const int pb = sb ^ 8;        // prefetch ring half
            doStep(0, sb, pb, tb + 8,  orow);
            doStep(1, sb, pb, tb + 9,  orow);
            doStep(2, sb, pb, tb + 10, orow);
            doStep(3, sb, pb, tb + 11, orow);
            doStep(4, sb, pb, tb + 12, orow);
            doStep(5, sb, pb, tb + 13, orow);
            doStep(6, sb, pb, tb + 14, orow);
            doStep(7, sb, pb, tb + 15, orow);
        } else if (tb != 0) {
            flushBuf(cur ^ 1, tb - CH);
        }
        sync_lds();                       // lgkm-only barrier: vm stays in flight
        cur ^= 1;
    }
    if (wid == 1) flushBuf(cur ^ 1, NT - CH);   // last block

    __builtin_amdgcn_s_setprio(0);
}

extern "C" void kernel_launch(void* const* d_in, const int* in_sizes, int n_in,
                              void* d_out, int out_size, void* d_ws, size_t ws_size,
                              hipStream_t stream) {
    const float* w         = (const float*)d_in[0];
    const float* ic        = (const float*)d_in[1];
    const float* v0        = (const float*)d_in[2];
    const float* i0        = (const float*)d_in[3];
    const float* s0        = (const float*)d_in[4];
    const float* mu        = (const float*)d_in[5];
    const float* sigma     = (const float*)d_in[6];
    const float* noise     = (const float*)d_in[7];
    const float* exp_draws = (const float*)d_in[8];
    float* out = (float*)d_out;

    (void)hipFuncSetAttribute((const void*)snn_scan_kernel,
                              hipFuncAttributeMaxDynamicSharedMemorySize,
                              LDS_BYTES);

    snn_scan_kernel<<<dim3(NS), dim3(128), LDS_BYTES, stream>>>(
        w, ic, v0, i0, s0, mu, sigma, noise, exp_draws, out);
}